// Round 10
// baseline (598.560 us; speedup 1.0000x reference)
//
#include <hip/hip_runtime.h>
#include <cstdint>
#include <cstddef>

// Dims (fixed by the problem)
#define BB 8
#define CC 128
#define C3 384
#define HH 64
#define H2 32
#define NPIX 1024   // 32*32
#define N4 4096     // 64*64
#define NHD 8
#define HD 16

typedef _Float16 h2f __attribute__((ext_vector_type(2)));

union HU { uint32_t u; h2f h; };
union U4H { uint4 u; h2f h[4]; };

__device__ inline h2f pkrtz(float a, float b) {
  return __builtin_bit_cast(h2f, __builtin_amdgcn_cvt_pkrtz(a, b));
}

__device__ inline h2f shflh(h2f v, int m) {
  HU x; x.h = v;
  x.u = (uint32_t)__shfl_xor((int)x.u, m);
  return x.h;
}

// ---------------- K1: Haar DWT ----------------
__global__ __launch_bounds__(256) void k_dwt(const float* __restrict__ x,
                                             float* __restrict__ ll,
                                             float* __restrict__ high) {
  int idx = blockIdx.x * 256 + threadIdx.x;   // B*C*32*32 = 1,048,576
  int w = idx & 31, h = (idx >> 5) & 31, c = (idx >> 10) & 127, b = idx >> 17;
  const float* xp = x + ((size_t)(b * CC + c) * HH + 2 * h) * HH + 2 * w;
  float x1 = xp[0];
  float x2 = xp[HH];
  float x3 = xp[1];
  float x4 = xp[HH + 1];
  int n = h * H2 + w;
  ll[(size_t)(b * CC + c) * NPIX + n]              = 0.5f * ( x1 + x2 + x3 + x4);
  high[((size_t)b * C3 + c) * NPIX + n]            = 0.5f * (-x1 - x2 + x3 + x4);
  high[((size_t)b * C3 + CC + c) * NPIX + n]       = 0.5f * (-x1 + x2 - x3 + x4);
  high[((size_t)b * C3 + 2 * CC + c) * NPIX + n]   = 0.5f * ( x1 - x2 - x3 + x4);
}

// ---------------- conv1x1: register GEMV (round-7 proven design) ----------------
template <int CIN, int P, int OPT>
__global__ __launch_bounds__(256) void k_conv1x1(const float* __restrict__ in,
                                                 const float* __restrict__ w,
                                                 float* __restrict__ out,
                                                 int Cout, int Npix) {
  int tid = threadIdx.x;
  int n0 = (blockIdx.x * 256 + tid) * P;
  int o0 = blockIdx.y * OPT;
  int b = blockIdx.z;
  const float* inb = in + (size_t)b * CIN * Npix + n0;
  const float* wb = w + (size_t)o0 * CIN;
  float acc[OPT][P];
#pragma unroll
  for (int o = 0; o < OPT; ++o)
#pragma unroll
    for (int p = 0; p < P; ++p) acc[o][p] = 0.f;

  for (int c0 = 0; c0 < CIN; c0 += 8) {
#pragma unroll
    for (int c = 0; c < 8; ++c) {
      float vv[P];
      const float* ip = inb + (size_t)(c0 + c) * Npix;
      if constexpr (P == 4) {
        float4 t = *(const float4*)ip;
        vv[0] = t.x; vv[1] = t.y; vv[2] = t.z; vv[3] = t.w;
      } else if constexpr (P == 2) {
        float2 t = *(const float2*)ip;
        vv[0] = t.x; vv[1] = t.y;
      } else {
        vv[0] = ip[0];
      }
#pragma unroll
      for (int o = 0; o < OPT; ++o) {
        float wc = wb[(size_t)o * CIN + c0 + c];   // uniform -> s_load
#pragma unroll
        for (int p = 0; p < P; ++p) acc[o][p] = fmaf(wc, vv[p], acc[o][p]);
      }
    }
  }
  size_t ob = ((size_t)b * Cout + o0) * Npix + n0;
#pragma unroll
  for (int o = 0; o < OPT; ++o) {
    float* op = out + ob + (size_t)o * Npix;
    if constexpr (P == 4) {
      *(float4*)op = make_float4(acc[o][0], acc[o][1], acc[o][2], acc[o][3]);
    } else if constexpr (P == 2) {
      *(float2*)op = make_float2(acc[o][0], acc[o][1]);
    } else {
      op[0] = acc[o][0];
    }
  }
}

// ---------------- fused qkv conv + l2norm + fp16 pack ----------------
__global__ __launch_bounds__(256) void k_conv_qkv(const float* __restrict__ in,
                                                  const float* __restrict__ w,
                                                  uint4* __restrict__ qh,
                                                  uint4* __restrict__ kh,
                                                  uint4* __restrict__ vh) {
  __shared__ float xs[32 * 64];
  int tid = threadIdx.x;
  int lane = tid & 63;
  int wv = tid >> 6;
  int n0 = blockIdx.x * 64;
  int c0out = blockIdx.y * 64 + wv * 16;    // first output channel of this wave
  int b = blockIdx.z;
  const float* inb = in + (size_t)b * CC * NPIX + n0 + lane;
  const float* wb = w + (size_t)c0out * CC;
  float acc[16];
#pragma unroll
  for (int o = 0; o < 16; ++o) acc[o] = 0.f;

  for (int c0 = 0; c0 < CC; c0 += 32) {
    __syncthreads();
#pragma unroll
    for (int i = 0; i < 8; ++i) {
      int c = wv * 8 + i;
      xs[c * 64 + lane] = inb[(size_t)(c0 + c) * NPIX];
    }
    __syncthreads();
#pragma unroll 4
    for (int c8 = 0; c8 < 32; c8 += 8) {
#pragma unroll
      for (int cc = 0; cc < 8; ++cc) {
        float v = xs[(c8 + cc) * 64 + lane];
#pragma unroll
        for (int o = 0; o < 16; ++o)
          acc[o] = fmaf(wb[(size_t)o * CC + c0 + c8 + cc], v, acc[o]);
      }
    }
  }
  int sec = c0out >> 7;               // 0=q, 1=k, 2=v
  int hd = (c0out & 127) >> 4;        // head index
  float ss = 0.f;
#pragma unroll
  for (int o = 0; o < 16; ++o) ss += acc[o] * acc[o];
  float r = (sec < 2) ? (1.f / fmaxf(sqrtf(ss), 1e-12f)) : 1.f;
  U4H p0, p1;
#pragma unroll
  for (int d = 0; d < 4; ++d) {
    p0.h[d] = pkrtz(acc[2 * d] * r, acc[2 * d + 1] * r);
    p1.h[d] = pkrtz(acc[8 + 2 * d] * r, acc[9 + 2 * d] * r);
  }
  uint4* dst = (sec == 0) ? qh : (sec == 1) ? kh : vh;
  size_t row = (size_t)(b * NHD + hd) * NPIX + n0 + lane;
  dst[row * 2]     = p0.u;
  dst[row * 2 + 1] = p1.u;
}

// ---------------- K3: sparse top-k attention, fp16, 8 q-rows/wave ----------------
// Block = 4 waves = 32 q-rows of one (b,h); grid 2048. Each wave streams all
// 1024 K rows once for 8 q-row dots (halved L2 traffic + 2x ILP vs Q4).
__global__ __launch_bounds__(256) void k_attn(const uint32_t* __restrict__ qh,
                                              const uint4* __restrict__ kh,
                                              const uint4* __restrict__ vh,
                                              float* __restrict__ attn_out) {
  __shared__ uint32_t q_lds[256];
  int tid = threadIdx.x;
  int lane = tid & 63;
  int wave = tid >> 6;
  int blk = blockIdx.x;            // 2048 blocks; 32 blocks per (b,h)
  int row0 = blk * 32;
  int bh = blk >> 5;
  q_lds[tid] = qh[(size_t)blk * 256 + tid];
  __syncthreads();
  h2f qs2[8][8];
  const uint32_t* qw = &q_lds[wave * 64];
#pragma unroll
  for (int q = 0; q < 8; ++q)
#pragma unroll
    for (int d = 0; d < 8; ++d) {
      HU u; u.u = qw[q * 8 + d];
      qs2[q][d] = u.h;
    }

  const uint4* kb = kh + (size_t)bh * 2048;   // 1024 rows * 2 uint4
  const uint4* vb = vh + (size_t)bh * 2048;

  // ---- phase 1: scores (fdot2, fp32 accum), packed into half2 ----
  h2f s2[8][8];
  float se[8];
#pragma unroll
  for (int i = 0; i < 16; ++i) {
    const uint4* kr = kb + (size_t)(i * 64 + lane) * 2;
    U4H u0, u1;
    u0.u = kr[0]; u1.u = kr[1];
    h2f k2[8];
#pragma unroll
    for (int d = 0; d < 4; ++d) { k2[d] = u0.h[d]; k2[4 + d] = u1.h[d]; }
#pragma unroll
    for (int q = 0; q < 8; ++q) {
      float acc = 0.f;
#pragma unroll
      for (int d = 0; d < 8; ++d)
        acc = __builtin_amdgcn_fdot2(qs2[q][d], k2[d], acc, false);
      acc *= 0.25f;                        // hd^-0.5; |acc| <= 0.25
      if (i & 1) s2[q][i >> 1] = pkrtz(se[q], acc);
      else       se[q] = acc;
    }
  }

  // ---- bisect for 512th-largest: f16 compare + ballot (SALU adds) ----
  float lo[8], hi[8];
  _Float16 hlo[8];
#pragma unroll
  for (int q = 0; q < 8; ++q) { lo[q] = -0.26f; hi[q] = 0.26f; hlo[q] = (_Float16)(-0.26f); }
  for (int it = 0; it < 12; ++it) {
#pragma unroll
    for (int q = 0; q < 8; ++q) {
      float mid = 0.5f * (lo[q] + hi[q]);
      _Float16 hm = (_Float16)mid;
      int c = 0;
#pragma unroll
      for (int j = 0; j < 8; ++j) {
        h2f t = s2[q][j];
        c += __popcll(__ballot(t[0] >= hm));
        c += __popcll(__ballot(t[1] >= hm));
      }
      if (c >= 512) { lo[q] = mid; hlo[q] = hm; } else hi[q] = mid;
    }
  }

  // ---- masked softmax in place (s2 -> unnormalized p, packed) ----
  float inv[8];
#pragma unroll
  for (int q = 0; q < 8; ++q) {
    float sum = 0.f;
#pragma unroll
    for (int j = 0; j < 8; ++j) {
      h2f t = s2[q][j];
      float p0 = (t[0] >= hlo[q]) ? __expf((float)t[0]) : 0.f;
      float p1 = (t[1] >= hlo[q]) ? __expf((float)t[1]) : 0.f;
      sum += p0 + p1;
      s2[q][j] = pkrtz(p0, p1);
    }
#pragma unroll
    for (int off = 32; off > 0; off >>= 1) sum += __shfl_xor(sum, off);
    inv[q] = 1.f / sum;
  }

  // ---- phase 2: AV (packed fp16 fma) ----
  h2f ov2[8][8];
#pragma unroll
  for (int q = 0; q < 8; ++q)
#pragma unroll
    for (int d = 0; d < 8; ++d) ov2[q][d] = (h2f)0;
#pragma unroll
  for (int i = 0; i < 16; ++i) {
    const uint4* vr = vb + (size_t)(i * 64 + lane) * 2;
    U4H u0, u1;
    u0.u = vr[0]; u1.u = vr[1];
    h2f v2[8];
#pragma unroll
    for (int d = 0; d < 4; ++d) { v2[d] = u0.h[d]; v2[4 + d] = u1.h[d]; }
#pragma unroll
    for (int q = 0; q < 8; ++q) {
      h2f t = s2[q][i >> 1];
      _Float16 pf = (i & 1) ? t[1] : t[0];
      h2f pp = (h2f){pf, pf};
#pragma unroll
      for (int d = 0; d < 8; ++d)
        ov2[q][d] = __builtin_elementwise_fma(pp, v2[d], ov2[q][d]);
    }
  }

  // ---- fold-transpose reduce (high/low split): lane L -> dim bitrev4(L) ----
  int b = bh >> 3, h = bh & 7;
  int dim = ((lane & 1) << 3) | ((lane & 2) << 1) | ((lane & 4) >> 1) | ((lane & 8) >> 3);
#pragma unroll
  for (int q = 0; q < 8; ++q) {
    bool m0 = (lane & 1) != 0;
    h2f B1[4];
#pragma unroll
    for (int p = 0; p < 4; ++p) {
      h2f r0 = shflh(ov2[q][p], 1);
      h2f r1 = shflh(ov2[q][p + 4], 1);
      h2f a0 = ov2[q][p] + r0;
      h2f a1 = ov2[q][p + 4] + r1;
      B1[p] = m0 ? a1 : a0;
    }
    bool m1 = (lane & 2) != 0;
    h2f B2[2];
#pragma unroll
    for (int p = 0; p < 2; ++p) {
      h2f r0 = shflh(B1[p], 2);
      h2f r1 = shflh(B1[p + 2], 2);
      h2f a0 = B1[p] + r0;
      h2f a1 = B1[p + 2] + r1;
      B2[p] = m1 ? a1 : a0;
    }
    bool m2 = (lane & 4) != 0;
    {
      h2f r0 = shflh(B2[0], 4);
      h2f r1 = shflh(B2[1], 4);
      h2f a0 = B2[0] + r0;
      h2f a1 = B2[1] + r1;
      B2[0] = m2 ? a1 : a0;
    }
    h2f r = shflh(B2[0], 8);
    h2f t = B2[0] + r;
    bool m3 = (lane & 8) != 0;
    float wf = m3 ? (float)t[1] : (float)t[0];
    wf += __shfl_xor(wf, 16);
    wf += __shfl_xor(wf, 32);
    if (lane < 16) {
      int n = (row0 + wave * 8 + q) & 1023;
      attn_out[((size_t)(b * CC + h * HD + dim) * NPIX) + n] = wf * inv[q];
    }
  }
}

// ---------------- fused depthwise 3x3 + GroupNorm + SiLU (1024 thr) ----------------
// One block per (b, group): 12 ch x 1024 px. 1024 threads = 16 waves/CU.
// Thread t: channels cslot*3..+3, pixel quad (t & 255)*4.
__global__ __launch_bounds__(1024) void k_dwgn(const float* __restrict__ high,
                                               const float* __restrict__ dww,
                                               const float* __restrict__ g1,
                                               const float* __restrict__ b1,
                                               float* __restrict__ y1) {
  int blk = blockIdx.x;           // b*32 + g
  int b = blk >> 5, g = blk & 31;
  int tid = threadIdx.x;
  int p0 = (tid & 255) * 4;       // 4 consecutive px, same row (4 | 32)
  int cslot = tid >> 8;           // 0..3 -> 3 channels each
  int row = p0 >> 5, col = p0 & 31;
  int c0 = g * 12 + cslot * 3;
  float r[3][4];
  float s = 0.f, s2 = 0.f;
#pragma unroll
  for (int c = 0; c < 3; ++c) {
    const float* inb = high + ((size_t)b * C3 + c0 + c) * NPIX;
    const float* wc = dww + (c0 + c) * 9;
    float win[3][6];
#pragma unroll
    for (int dr = -1; dr <= 1; ++dr) {
      int rr = row + dr;
      bool rok = (rr >= 0) && (rr < 32);
#pragma unroll
      for (int dc = -1; dc <= 4; ++dc) {
        int cc2 = col + dc;
        bool cok = (cc2 >= 0) && (cc2 < 32);
        win[dr + 1][dc + 1] = (rok && cok) ? inb[rr * 32 + cc2] : 0.f;
      }
    }
#pragma unroll
    for (int p = 0; p < 4; ++p) {
      float a = 0.f;
#pragma unroll
      for (int i = 0; i < 3; ++i)
#pragma unroll
        for (int j = 0; j < 3; ++j)
          a = fmaf(win[i][p + j], wc[i * 3 + j], a);
      r[c][p] = a;
      s += a;
      s2 += a * a;
    }
  }
  // block reduce (16 waves)
#pragma unroll
  for (int off = 32; off > 0; off >>= 1) {
    s += __shfl_xor(s, off);
    s2 += __shfl_xor(s2, off);
  }
  __shared__ float ls[16], ls2[16];
  int wv = tid >> 6, ln = tid & 63;
  if (ln == 0) { ls[wv] = s; ls2[wv] = s2; }
  __syncthreads();
  float st = 0.f, s2t = 0.f;
#pragma unroll
  for (int i = 0; i < 16; ++i) { st += ls[i]; s2t += ls2[i]; }
  const float inv_n = 1.f / 12288.f;
  float mean = st * inv_n;
  float var = s2t * inv_n - mean * mean;
  float rstd = rsqrtf(var + 1e-6f);
#pragma unroll
  for (int c = 0; c < 3; ++c) {
    float gm = g1[c0 + c], bt = b1[c0 + c];
    float o[4];
#pragma unroll
    for (int p = 0; p < 4; ++p) {
      float gnv = (r[c][p] - mean) * rstd * gm + bt;
      o[p] = gnv / (1.f + __expf(-gnv));     // silu
    }
    float* op = y1 + ((size_t)b * C3 + c0 + c) * NPIX + p0;
    *(float4*)op = make_float4(o[0], o[1], o[2], o[3]);
  }
}

// ---------------- GroupNorm (32 groups) + fused epilogue, float4, 512 thr ----
template <int ACT, bool HAS_RES>
__global__ __launch_bounds__(512) void k_gn(const float* __restrict__ x,
                                            const float* __restrict__ res,
                                            float* __restrict__ out,
                                            const float* __restrict__ gamma,
                                            const float* __restrict__ beta,
                                            const float* __restrict__ alpha_ptr,
                                            float alpha_const,
                                            int chPerGroup, int Npix, int nshift) {
  int g = blockIdx.x & 31, b = blockIdx.x >> 5;
  int Cout = 32 * chPerGroup;
  int elems = chPerGroup * Npix;
  int nv = elems >> 2;
  size_t base = ((size_t)b * Cout + g * chPerGroup) * Npix;
  const float4* xv = (const float4*)(x + base);
  int tid = threadIdx.x;
  float s = 0.f, s2 = 0.f;
  for (int i = tid; i < nv; i += 512) {
    float4 v = xv[i];
    s += v.x + v.y + v.z + v.w;
    s2 += v.x * v.x + v.y * v.y + v.z * v.z + v.w * v.w;
  }
#pragma unroll
  for (int off = 32; off > 0; off >>= 1) {
    s += __shfl_xor(s, off);
    s2 += __shfl_xor(s2, off);
  }
  __shared__ float ls[8], ls2[8];
  int wv = tid >> 6, ln = tid & 63;
  if (ln == 0) { ls[wv] = s; ls2[wv] = s2; }
  __syncthreads();
  float st = 0.f, s2t = 0.f;
#pragma unroll
  for (int i = 0; i < 8; ++i) { st += ls[i]; s2t += ls2[i]; }
  float inv_n = 1.f / (float)elems;
  float mean = st * inv_n;
  float var = s2t * inv_n - mean * mean;
  float rstd = rsqrtf(var + 1e-6f);
  float a = alpha_ptr ? alpha_ptr[0] : alpha_const;
  const float4* rv = (const float4*)(res + base);
  float4* ov = (float4*)(out + base);
  int cshift = nshift - 2;
  for (int i = tid; i < nv; i += 512) {
    float4 v = xv[i];
    int cc = g * chPerGroup + (i >> cshift);
    float gm = gamma[cc], bt = beta[cc];
    float r[4] = {v.x, v.y, v.z, v.w};
#pragma unroll
    for (int p = 0; p < 4; ++p) {
      float gnv = (r[p] - mean) * rstd * gm + bt;
      if (ACT == 1)      r[p] = gnv / (1.f + __expf(-gnv));
      else if (ACT == 2) r[p] = 0.5f * gnv * (1.f + erff(gnv * 0.70710678118654752f));
      else               r[p] = gnv;
    }
    float4 o;
    if (HAS_RES) {
      float4 rr = rv[i];
      o = make_float4(rr.x + a * r[0], rr.y + a * r[1], rr.z + a * r[2], rr.w + a * r[3]);
    } else {
      o = make_float4(r[0], r[1], r[2], r[3]);
    }
    ov[i] = o;
  }
}

// ---------------- K6: IWT + residual ----------------
__global__ __launch_bounds__(256) void k_iwt(const float* __restrict__ x,
                                             const float* __restrict__ s1,
                                             const float* __restrict__ hout,
                                             float* __restrict__ out) {
  int idx = blockIdx.x * 256 + threadIdx.x;  // B*C*32*32
  int w = idx & 31, h = (idx >> 5) & 31, c = (idx >> 10) & 127, b = idx >> 17;
  int n = h * 32 + w;
  float ll = s1[(size_t)(b * CC + c) * NPIX + n];
  float lh = hout[((size_t)b * C3 + c) * NPIX + n];
  float hl = hout[((size_t)b * C3 + CC + c) * NPIX + n];
  float hh = hout[((size_t)b * C3 + 2 * CC + c) * NPIX + n];
  float va = ll - lh - hl + hh;
  float vb = ll - lh + hl - hh;
  float vc = ll + lh - hl - hh;
  float vd = ll + lh + hl + hh;
  size_t xb = ((size_t)(b * CC + c) * HH + 2 * h) * HH + 2 * w;
  out[xb]          = x[xb]          + 0.1f * va;
  out[xb + 1]      = x[xb + 1]      + 0.1f * vc;
  out[xb + HH]     = x[xb + HH]     + 0.1f * vb;
  out[xb + HH + 1] = x[xb + HH + 1] + 0.1f * vd;
}

extern "C" void kernel_launch(void* const* d_in, const int* in_sizes, int n_in,
                              void* d_out, int out_size, void* d_ws, size_t ws_size,
                              hipStream_t stream) {
  const float* x         = (const float*)d_in[0];
  const float* qkv_w     = (const float*)d_in[1];
  const float* proj_w    = (const float*)d_in[2];
  const float* attn_gn_g = (const float*)d_in[3];
  const float* attn_gn_b = (const float*)d_in[4];
  const float* he_dw_w   = (const float*)d_in[5];
  const float* he_gn1_g  = (const float*)d_in[6];
  const float* he_gn1_b  = (const float*)d_in[7];
  const float* he_pw_w   = (const float*)d_in[8];
  const float* he_gn2_g  = (const float*)d_in[9];
  const float* he_gn2_b  = (const float*)d_in[10];
  const float* alpha     = (const float*)d_in[11];
  const float* ffn_w1    = (const float*)d_in[12];
  const float* ffn_gn1_g = (const float*)d_in[13];
  const float* ffn_gn1_b = (const float*)d_in[14];
  const float* ffn_w2    = (const float*)d_in[15];
  const float* ffn_gn2_g = (const float*)d_in[16];
  const float* ffn_gn2_b = (const float*)d_in[17];
  float* out = (float*)d_out;

  float* ws = (float*)d_ws;
  float* ll   = ws;              // 1,048,576
  float* high = ws + 1048576;    // 3,145,728
  float* y1   = ws + 4194304;    // 3,145,728 (fused dw+gn out)
  float* qnkv = ws + 7340032;    // 3,145,728 ; qh|kh|vh (fp16) ; reused as pw/h_out
  float* atto = ws + 10485760;   // 1,048,576
  float* proj = ws + 11534336;   // 1,048,576
  float* f1   = ws + 12582912;   // 8,388,608
  float* f3   = ws + 20971520;   // 4,194,304
  uint4* qh = (uint4*)qnkv;
  uint4* kh = (uint4*)(qnkv + 524288);
  uint4* vh = (uint4*)(qnkv + 1048576);
  float* pw = qnkv;

  // 1) DWT
  k_dwt<<<4096, 256, 0, stream>>>(x, ll, high);
  // 2) fused qkv conv + l2norm + fp16 pack
  k_conv_qkv<<<dim3(16, 6, 8), 256, 0, stream>>>(ll, qkv_w, qh, kh, vh);
  // 3) sparse attention (8 q-rows per wave, fp16-packed state)
  k_attn<<<2048, 256, 0, stream>>>((const uint32_t*)qh, kh, vh, atto);
  // 4) proj + groupnorm, s1 = ll + gn(proj)
  k_conv1x1<128, 1, 4><<<dim3(4, 32, 8), 256, 0, stream>>>(atto, proj_w, proj, 128, 1024);
  k_gn<0, true><<<256, 512, 0, stream>>>(proj, ll, proj, attn_gn_g, attn_gn_b,
                                         nullptr, 1.0f, 4, 1024, 10);
  // 5) high enhance: fused dwconv+GN1+silu, then pointwise conv, then GN2
  k_dwgn<<<256, 1024, 0, stream>>>(high, he_dw_w, he_gn1_g, he_gn1_b, y1);
  k_conv1x1<384, 1, 8><<<dim3(4, 48, 8), 256, 0, stream>>>(y1, he_pw_w, pw, 384, 1024);
  k_gn<0, true><<<256, 512, 0, stream>>>(pw, high, pw, he_gn2_g, he_gn2_b,
                                         alpha, 0.f, 12, 1024, 10);
  // 6) IWT + residual -> out
  k_iwt<<<4096, 256, 0, stream>>>(x, proj, pw, out);
  // 7) FFN
  k_conv1x1<128, 2, 8><<<dim3(8, 32, 8), 256, 0, stream>>>(out, ffn_w1, f1, 256, 4096);
  k_gn<2, false><<<256, 512, 0, stream>>>(f1, nullptr, f1, ffn_gn1_g, ffn_gn1_b,
                                          nullptr, 0.f, 8, 4096, 12);
  k_conv1x1<256, 2, 8><<<dim3(8, 16, 8), 256, 0, stream>>>(f1, ffn_w2, f3, 128, 4096);
  k_gn<0, true><<<256, 512, 0, stream>>>(f3, out, out, ffn_gn2_g, ffn_gn2_b,
                                         nullptr, 0.1f, 4, 4096, 12);
  (void)in_sizes; (void)n_in; (void)out_size; (void)ws_size;
}

// Round 11
// 485.551 us; speedup vs baseline: 1.2327x; 1.2327x over previous
//
#include <hip/hip_runtime.h>
#include <cstdint>
#include <cstddef>

// Dims (fixed by the problem)
#define BB 8
#define CC 128
#define C3 384
#define HH 64
#define H2 32
#define NPIX 1024   // 32*32
#define N4 4096     // 64*64
#define NHD 8
#define HD 16

typedef _Float16 h2f __attribute__((ext_vector_type(2)));

union HU { uint32_t u; h2f h; };
union U4H { uint4 u; h2f h[4]; };

__device__ inline h2f pkrtz(float a, float b) {
  return __builtin_bit_cast(h2f, __builtin_amdgcn_cvt_pkrtz(a, b));
}

__device__ inline h2f shflh(h2f v, int m) {
  HU x; x.h = v;
  x.u = (uint32_t)__shfl_xor((int)x.u, m);
  return x.h;
}

// ---------------- K1: Haar DWT (vectorized: float4 in, float2 out) ----------------
__global__ __launch_bounds__(256) void k_dwt(const float* __restrict__ x,
                                             float* __restrict__ ll,
                                             float* __restrict__ high) {
  int idx = blockIdx.x * 256 + threadIdx.x;   // B*C*32*16 = 524,288
  int w4 = idx & 15, h = (idx >> 4) & 31, c = (idx >> 9) & 127, b = idx >> 16;
  const float* xp = x + ((size_t)(b * CC + c) * HH + 2 * h) * HH + 4 * w4;
  float4 e = *(const float4*)xp;        // even row, cols 4w4..4w4+3
  float4 o = *(const float4*)(xp + HH); // odd row
  int n = h * H2 + 2 * w4;
  // pixel0: x1=e.x x2=o.x x3=e.y x4=o.y ; pixel1: e.z o.z e.w o.w
  float2 llv = make_float2(0.5f * ( e.x + o.x + e.y + o.y), 0.5f * ( e.z + o.z + e.w + o.w));
  float2 lhv = make_float2(0.5f * (-e.x - o.x + e.y + o.y), 0.5f * (-e.z - o.z + e.w + o.w));
  float2 hlv = make_float2(0.5f * (-e.x + o.x - e.y + o.y), 0.5f * (-e.z + o.z - e.w + o.w));
  float2 hhv = make_float2(0.5f * ( e.x - o.x - e.y + o.y), 0.5f * ( e.z - o.z - e.w + o.w));
  *(float2*)&ll[(size_t)(b * CC + c) * NPIX + n]            = llv;
  *(float2*)&high[((size_t)b * C3 + c) * NPIX + n]          = lhv;
  *(float2*)&high[((size_t)b * C3 + CC + c) * NPIX + n]     = hlv;
  *(float2*)&high[((size_t)b * C3 + 2 * CC + c) * NPIX + n] = hhv;
}

// ---------------- conv1x1: register GEMV (round-7 proven design) ----------------
template <int CIN, int P, int OPT>
__global__ __launch_bounds__(256) void k_conv1x1(const float* __restrict__ in,
                                                 const float* __restrict__ w,
                                                 float* __restrict__ out,
                                                 int Cout, int Npix) {
  int tid = threadIdx.x;
  int n0 = (blockIdx.x * 256 + tid) * P;
  int o0 = blockIdx.y * OPT;
  int b = blockIdx.z;
  const float* inb = in + (size_t)b * CIN * Npix + n0;
  const float* wb = w + (size_t)o0 * CIN;
  float acc[OPT][P];
#pragma unroll
  for (int o = 0; o < OPT; ++o)
#pragma unroll
    for (int p = 0; p < P; ++p) acc[o][p] = 0.f;

  for (int c0 = 0; c0 < CIN; c0 += 8) {
#pragma unroll
    for (int c = 0; c < 8; ++c) {
      float vv[P];
      const float* ip = inb + (size_t)(c0 + c) * Npix;
      if constexpr (P == 4) {
        float4 t = *(const float4*)ip;
        vv[0] = t.x; vv[1] = t.y; vv[2] = t.z; vv[3] = t.w;
      } else if constexpr (P == 2) {
        float2 t = *(const float2*)ip;
        vv[0] = t.x; vv[1] = t.y;
      } else {
        vv[0] = ip[0];
      }
#pragma unroll
      for (int o = 0; o < OPT; ++o) {
        float wc = wb[(size_t)o * CIN + c0 + c];   // uniform -> s_load
#pragma unroll
        for (int p = 0; p < P; ++p) acc[o][p] = fmaf(wc, vv[p], acc[o][p]);
      }
    }
  }
  size_t ob = ((size_t)b * Cout + o0) * Npix + n0;
#pragma unroll
  for (int o = 0; o < OPT; ++o) {
    float* op = out + ob + (size_t)o * Npix;
    if constexpr (P == 4) {
      *(float4*)op = make_float4(acc[o][0], acc[o][1], acc[o][2], acc[o][3]);
    } else if constexpr (P == 2) {
      *(float2*)op = make_float2(acc[o][0], acc[o][1]);
    } else {
      op[0] = acc[o][0];
    }
  }
}

// ---------------- fused qkv conv + l2norm + fp16 pack ----------------
__global__ __launch_bounds__(256) void k_conv_qkv(const float* __restrict__ in,
                                                  const float* __restrict__ w,
                                                  uint4* __restrict__ qh,
                                                  uint4* __restrict__ kh,
                                                  uint4* __restrict__ vh) {
  __shared__ float xs[32 * 64];
  int tid = threadIdx.x;
  int lane = tid & 63;
  int wv = tid >> 6;
  int n0 = blockIdx.x * 64;
  int c0out = blockIdx.y * 64 + wv * 16;    // first output channel of this wave
  int b = blockIdx.z;
  const float* inb = in + (size_t)b * CC * NPIX + n0 + lane;
  const float* wb = w + (size_t)c0out * CC;
  float acc[16];
#pragma unroll
  for (int o = 0; o < 16; ++o) acc[o] = 0.f;

  for (int c0 = 0; c0 < CC; c0 += 32) {
    __syncthreads();
#pragma unroll
    for (int i = 0; i < 8; ++i) {
      int c = wv * 8 + i;
      xs[c * 64 + lane] = inb[(size_t)(c0 + c) * NPIX];
    }
    __syncthreads();
#pragma unroll 4
    for (int c8 = 0; c8 < 32; c8 += 8) {
#pragma unroll
      for (int cc = 0; cc < 8; ++cc) {
        float v = xs[(c8 + cc) * 64 + lane];
#pragma unroll
        for (int o = 0; o < 16; ++o)
          acc[o] = fmaf(wb[(size_t)o * CC + c0 + c8 + cc], v, acc[o]);
      }
    }
  }
  int sec = c0out >> 7;               // 0=q, 1=k, 2=v
  int hd = (c0out & 127) >> 4;        // head index
  float ss = 0.f;
#pragma unroll
  for (int o = 0; o < 16; ++o) ss += acc[o] * acc[o];
  float r = (sec < 2) ? (1.f / fmaxf(sqrtf(ss), 1e-12f)) : 1.f;
  U4H p0, p1;
#pragma unroll
  for (int d = 0; d < 4; ++d) {
    p0.h[d] = pkrtz(acc[2 * d] * r, acc[2 * d + 1] * r);
    p1.h[d] = pkrtz(acc[8 + 2 * d] * r, acc[9 + 2 * d] * r);
  }
  uint4* dst = (sec == 0) ? qh : (sec == 1) ? kh : vh;
  size_t row = (size_t)(b * NHD + hd) * NPIX + n0 + lane;
  dst[row * 2]     = p0.u;
  dst[row * 2 + 1] = p1.u;
}

// ---------------- K3: sparse top-k attention, fp16, 4 q-rows/wave ----------------
// XCD-swizzled: all 64 blocks of one (b,h) map to one XCD (hw: XCD = p%8)
// so its 64 KB K+V stays hot in that XCD's L2. 2-deep explicit prefetch
// keeps >=2 loads in flight per wave. ~105 VGPR -> 5 waves/SIMD cap
// (round-10 lesson: achieved occupancy tracks the VGPR cap).
__global__ __launch_bounds__(256) void k_attn(const uint32_t* __restrict__ qh,
                                              const uint4* __restrict__ kh,
                                              const uint4* __restrict__ vh,
                                              float* __restrict__ attn_out) {
  __shared__ uint32_t q_lds[128];
  int p = blockIdx.x;                 // 4096 blocks
  int xcd = p & 7, sub = (p >> 3) & 63, grpp = p >> 9;
  int bh = grpp * 8 + xcd;            // all sub-blocks of bh share XCD
  int blk = bh * 64 + sub;
  int row0 = blk * 16;
  int tid = threadIdx.x;
  int lane = tid & 63;
  int wave = tid >> 6;
  if (tid < 128) q_lds[tid] = qh[(size_t)blk * 128 + tid];
  __syncthreads();
  h2f qs2[4][8];
  const uint32_t* qw = &q_lds[wave * 32];
#pragma unroll
  for (int q = 0; q < 4; ++q)
#pragma unroll
    for (int d = 0; d < 8; ++d) {
      HU u; u.u = qw[q * 8 + d];
      qs2[q][d] = u.h;
    }

  const uint4* kb = kh + (size_t)bh * 2048;   // 1024 rows * 2 uint4
  const uint4* vb = vh + (size_t)bh * 2048;

  // ---- phase 1: scores (fdot2, fp32 accum), 2-deep prefetch ----
  h2f s2[4][8];
  float se[4];
  uint4 cu0 = kb[(size_t)lane * 2], cu1 = kb[(size_t)lane * 2 + 1];
#pragma unroll
  for (int i = 0; i < 16; ++i) {
    uint4 nu0, nu1;
    if (i < 15) {
      const uint4* nr = kb + (size_t)((i + 1) * 64 + lane) * 2;
      nu0 = nr[0]; nu1 = nr[1];
    }
    U4H u0, u1;
    u0.u = cu0; u1.u = cu1;
    h2f k2[8];
#pragma unroll
    for (int d = 0; d < 4; ++d) { k2[d] = u0.h[d]; k2[4 + d] = u1.h[d]; }
#pragma unroll
    for (int q = 0; q < 4; ++q) {
      float acc = 0.f;
#pragma unroll
      for (int d = 0; d < 8; ++d)
        acc = __builtin_amdgcn_fdot2(qs2[q][d], k2[d], acc, false);
      acc *= 0.25f;                        // hd^-0.5; |acc| <= 0.25
      if (i & 1) s2[q][i >> 1] = pkrtz(se[q], acc);
      else       se[q] = acc;
    }
    cu0 = nu0; cu1 = nu1;
  }

  // ---- bisect for 512th-largest: f16 compare + ballot (SALU adds) ----
  float lo[4], hi[4];
  _Float16 hlo[4];
#pragma unroll
  for (int q = 0; q < 4; ++q) { lo[q] = -0.26f; hi[q] = 0.26f; hlo[q] = (_Float16)(-0.26f); }
  for (int it = 0; it < 12; ++it) {
#pragma unroll
    for (int q = 0; q < 4; ++q) {
      float mid = 0.5f * (lo[q] + hi[q]);
      _Float16 hm = (_Float16)mid;
      int c = 0;
#pragma unroll
      for (int j = 0; j < 8; ++j) {
        h2f t = s2[q][j];
        c += __popcll(__ballot(t[0] >= hm));
        c += __popcll(__ballot(t[1] >= hm));
      }
      if (c >= 512) { lo[q] = mid; hlo[q] = hm; } else hi[q] = mid;
    }
  }

  // ---- masked softmax in place (s2 -> unnormalized p, packed) ----
  float inv[4];
#pragma unroll
  for (int q = 0; q < 4; ++q) {
    float sum = 0.f;
#pragma unroll
    for (int j = 0; j < 8; ++j) {
      h2f t = s2[q][j];
      float p0 = (t[0] >= hlo[q]) ? __expf((float)t[0]) : 0.f;
      float p1 = (t[1] >= hlo[q]) ? __expf((float)t[1]) : 0.f;
      sum += p0 + p1;
      s2[q][j] = pkrtz(p0, p1);
    }
#pragma unroll
    for (int off = 32; off > 0; off >>= 1) sum += __shfl_xor(sum, off);
    inv[q] = 1.f / sum;
  }

  // ---- phase 2: AV (packed fp16 fma), 2-deep prefetch ----
  h2f ov2[4][8];
#pragma unroll
  for (int q = 0; q < 4; ++q)
#pragma unroll
    for (int d = 0; d < 8; ++d) ov2[q][d] = (h2f)0;
  cu0 = vb[(size_t)lane * 2]; cu1 = vb[(size_t)lane * 2 + 1];
#pragma unroll
  for (int i = 0; i < 16; ++i) {
    uint4 nu0, nu1;
    if (i < 15) {
      const uint4* nr = vb + (size_t)((i + 1) * 64 + lane) * 2;
      nu0 = nr[0]; nu1 = nr[1];
    }
    U4H u0, u1;
    u0.u = cu0; u1.u = cu1;
    h2f v2[8];
#pragma unroll
    for (int d = 0; d < 4; ++d) { v2[d] = u0.h[d]; v2[4 + d] = u1.h[d]; }
#pragma unroll
    for (int q = 0; q < 4; ++q) {
      h2f t = s2[q][i >> 1];
      _Float16 pf = (i & 1) ? t[1] : t[0];
      h2f pp = (h2f){pf, pf};
#pragma unroll
      for (int d = 0; d < 8; ++d)
        ov2[q][d] = __builtin_elementwise_fma(pp, v2[d], ov2[q][d]);
    }
    cu0 = nu0; cu1 = nu1;
  }

  // ---- fold-transpose reduce (high/low split): lane L -> dim bitrev4(L) ----
  int b = bh >> 3, h = bh & 7;
  int dim = ((lane & 1) << 3) | ((lane & 2) << 1) | ((lane & 4) >> 1) | ((lane & 8) >> 3);
#pragma unroll
  for (int q = 0; q < 4; ++q) {
    bool m0 = (lane & 1) != 0;
    h2f B1[4];
#pragma unroll
    for (int pp = 0; pp < 4; ++pp) {
      h2f r0 = shflh(ov2[q][pp], 1);
      h2f r1 = shflh(ov2[q][pp + 4], 1);
      h2f a0 = ov2[q][pp] + r0;
      h2f a1 = ov2[q][pp + 4] + r1;
      B1[pp] = m0 ? a1 : a0;
    }
    bool m1 = (lane & 2) != 0;
    h2f B2[2];
#pragma unroll
    for (int pp = 0; pp < 2; ++pp) {
      h2f r0 = shflh(B1[pp], 2);
      h2f r1 = shflh(B1[pp + 2], 2);
      h2f a0 = B1[pp] + r0;
      h2f a1 = B1[pp + 2] + r1;
      B2[pp] = m1 ? a1 : a0;
    }
    bool m2 = (lane & 4) != 0;
    {
      h2f r0 = shflh(B2[0], 4);
      h2f r1 = shflh(B2[1], 4);
      h2f a0 = B2[0] + r0;
      h2f a1 = B2[1] + r1;
      B2[0] = m2 ? a1 : a0;
    }
    h2f r = shflh(B2[0], 8);
    h2f t = B2[0] + r;
    bool m3 = (lane & 8) != 0;
    float wf = m3 ? (float)t[1] : (float)t[0];
    wf += __shfl_xor(wf, 16);
    wf += __shfl_xor(wf, 32);
    if (lane < 16) {
      int n = (row0 + wave * 4 + q) & 1023;
      attn_out[((size_t)(b * CC + h * HD + dim) * NPIX) + n] = wf * inv[q];
    }
  }
}

// ---------------- fused depthwise 3x3 + GroupNorm + SiLU (1024 thr) ----------------
__global__ __launch_bounds__(1024) void k_dwgn(const float* __restrict__ high,
                                               const float* __restrict__ dww,
                                               const float* __restrict__ g1,
                                               const float* __restrict__ b1,
                                               float* __restrict__ y1) {
  int blk = blockIdx.x;           // b*32 + g
  int b = blk >> 5, g = blk & 31;
  int tid = threadIdx.x;
  int p0 = (tid & 255) * 4;       // 4 consecutive px, same row (4 | 32)
  int cslot = tid >> 8;           // 0..3 -> 3 channels each
  int row = p0 >> 5, col = p0 & 31;
  int c0 = g * 12 + cslot * 3;
  float r[3][4];
  float s = 0.f, s2 = 0.f;
#pragma unroll
  for (int c = 0; c < 3; ++c) {
    const float* inb = high + ((size_t)b * C3 + c0 + c) * NPIX;
    const float* wc = dww + (c0 + c) * 9;
    float win[3][6];
#pragma unroll
    for (int dr = -1; dr <= 1; ++dr) {
      int rr = row + dr;
      bool rok = (rr >= 0) && (rr < 32);
#pragma unroll
      for (int dc = -1; dc <= 4; ++dc) {
        int cc2 = col + dc;
        bool cok = (cc2 >= 0) && (cc2 < 32);
        win[dr + 1][dc + 1] = (rok && cok) ? inb[rr * 32 + cc2] : 0.f;
      }
    }
#pragma unroll
    for (int p = 0; p < 4; ++p) {
      float a = 0.f;
#pragma unroll
      for (int i = 0; i < 3; ++i)
#pragma unroll
        for (int j = 0; j < 3; ++j)
          a = fmaf(win[i][p + j], wc[i * 3 + j], a);
      r[c][p] = a;
      s += a;
      s2 += a * a;
    }
  }
#pragma unroll
  for (int off = 32; off > 0; off >>= 1) {
    s += __shfl_xor(s, off);
    s2 += __shfl_xor(s2, off);
  }
  __shared__ float ls[16], ls2[16];
  int wv = tid >> 6, ln = tid & 63;
  if (ln == 0) { ls[wv] = s; ls2[wv] = s2; }
  __syncthreads();
  float st = 0.f, s2t = 0.f;
#pragma unroll
  for (int i = 0; i < 16; ++i) { st += ls[i]; s2t += ls2[i]; }
  const float inv_n = 1.f / 12288.f;
  float mean = st * inv_n;
  float var = s2t * inv_n - mean * mean;
  float rstd = rsqrtf(var + 1e-6f);
#pragma unroll
  for (int c = 0; c < 3; ++c) {
    float gm = g1[c0 + c], bt = b1[c0 + c];
    float o[4];
#pragma unroll
    for (int p = 0; p < 4; ++p) {
      float gnv = (r[c][p] - mean) * rstd * gm + bt;
      o[p] = gnv / (1.f + __expf(-gnv));     // silu
    }
    float* op = y1 + ((size_t)b * C3 + c0 + c) * NPIX + p0;
    *(float4*)op = make_float4(o[0], o[1], o[2], o[3]);
  }
}

// ---------------- GroupNorm (32 groups) + fused epilogue, float4, 512 thr ----
template <int ACT, bool HAS_RES>
__global__ __launch_bounds__(512) void k_gn(const float* __restrict__ x,
                                            const float* __restrict__ res,
                                            float* __restrict__ out,
                                            const float* __restrict__ gamma,
                                            const float* __restrict__ beta,
                                            const float* __restrict__ alpha_ptr,
                                            float alpha_const,
                                            int chPerGroup, int Npix, int nshift) {
  int g = blockIdx.x & 31, b = blockIdx.x >> 5;
  int Cout = 32 * chPerGroup;
  int elems = chPerGroup * Npix;
  int nv = elems >> 2;
  size_t base = ((size_t)b * Cout + g * chPerGroup) * Npix;
  const float4* xv = (const float4*)(x + base);
  int tid = threadIdx.x;
  float s = 0.f, s2 = 0.f;
  for (int i = tid; i < nv; i += 512) {
    float4 v = xv[i];
    s += v.x + v.y + v.z + v.w;
    s2 += v.x * v.x + v.y * v.y + v.z * v.z + v.w * v.w;
  }
#pragma unroll
  for (int off = 32; off > 0; off >>= 1) {
    s += __shfl_xor(s, off);
    s2 += __shfl_xor(s2, off);
  }
  __shared__ float ls[8], ls2[8];
  int wv = tid >> 6, ln = tid & 63;
  if (ln == 0) { ls[wv] = s; ls2[wv] = s2; }
  __syncthreads();
  float st = 0.f, s2t = 0.f;
#pragma unroll
  for (int i = 0; i < 8; ++i) { st += ls[i]; s2t += ls2[i]; }
  float inv_n = 1.f / (float)elems;
  float mean = st * inv_n;
  float var = s2t * inv_n - mean * mean;
  float rstd = rsqrtf(var + 1e-6f);
  float a = alpha_ptr ? alpha_ptr[0] : alpha_const;
  const float4* rv = (const float4*)(res + base);
  float4* ov = (float4*)(out + base);
  int cshift = nshift - 2;
  for (int i = tid; i < nv; i += 512) {
    float4 v = xv[i];
    int cc = g * chPerGroup + (i >> cshift);
    float gm = gamma[cc], bt = beta[cc];
    float r[4] = {v.x, v.y, v.z, v.w};
#pragma unroll
    for (int p = 0; p < 4; ++p) {
      float gnv = (r[p] - mean) * rstd * gm + bt;
      if (ACT == 1)      r[p] = gnv / (1.f + __expf(-gnv));
      else if (ACT == 2) r[p] = 0.5f * gnv * (1.f + erff(gnv * 0.70710678118654752f));
      else               r[p] = gnv;
    }
    float4 o;
    if (HAS_RES) {
      float4 rr = rv[i];
      o = make_float4(rr.x + a * r[0], rr.y + a * r[1], rr.z + a * r[2], rr.w + a * r[3]);
    } else {
      o = make_float4(r[0], r[1], r[2], r[3]);
    }
    ov[i] = o;
  }
}

// ---------------- K6: IWT + residual (vectorized) ----------------
__global__ __launch_bounds__(256) void k_iwt(const float* __restrict__ x,
                                             const float* __restrict__ s1,
                                             const float* __restrict__ hout,
                                             float* __restrict__ out) {
  int idx = blockIdx.x * 256 + threadIdx.x;  // B*C*32*16 = 524,288
  int w2 = idx & 15, h = (idx >> 4) & 31, c = (idx >> 9) & 127, b = idx >> 16;
  int n = h * 32 + 2 * w2;
  float2 ll = *(const float2*)&s1[(size_t)(b * CC + c) * NPIX + n];
  float2 lh = *(const float2*)&hout[((size_t)b * C3 + c) * NPIX + n];
  float2 hl = *(const float2*)&hout[((size_t)b * C3 + CC + c) * NPIX + n];
  float2 hh = *(const float2*)&hout[((size_t)b * C3 + 2 * CC + c) * NPIX + n];
  // per pixel: va(even r,even c) vc(even r,odd c) vb(odd r,even c) vd(odd r,odd c)
  float va0 = ll.x - lh.x - hl.x + hh.x, va1 = ll.y - lh.y - hl.y + hh.y;
  float vb0 = ll.x - lh.x + hl.x - hh.x, vb1 = ll.y - lh.y + hl.y - hh.y;
  float vc0 = ll.x + lh.x - hl.x - hh.x, vc1 = ll.y + lh.y - hl.y - hh.y;
  float vd0 = ll.x + lh.x + hl.x + hh.x, vd1 = ll.y + lh.y + hl.y + hh.y;
  size_t xb = ((size_t)(b * CC + c) * HH + 2 * h) * HH + 4 * w2;
  float4 xe = *(const float4*)&x[xb];
  float4 xo = *(const float4*)&x[xb + HH];
  *(float4*)&out[xb]      = make_float4(xe.x + 0.1f * va0, xe.y + 0.1f * vc0,
                                        xe.z + 0.1f * va1, xe.w + 0.1f * vc1);
  *(float4*)&out[xb + HH] = make_float4(xo.x + 0.1f * vb0, xo.y + 0.1f * vd0,
                                        xo.z + 0.1f * vb1, xo.w + 0.1f * vd1);
}

extern "C" void kernel_launch(void* const* d_in, const int* in_sizes, int n_in,
                              void* d_out, int out_size, void* d_ws, size_t ws_size,
                              hipStream_t stream) {
  const float* x         = (const float*)d_in[0];
  const float* qkv_w     = (const float*)d_in[1];
  const float* proj_w    = (const float*)d_in[2];
  const float* attn_gn_g = (const float*)d_in[3];
  const float* attn_gn_b = (const float*)d_in[4];
  const float* he_dw_w   = (const float*)d_in[5];
  const float* he_gn1_g  = (const float*)d_in[6];
  const float* he_gn1_b  = (const float*)d_in[7];
  const float* he_pw_w   = (const float*)d_in[8];
  const float* he_gn2_g  = (const float*)d_in[9];
  const float* he_gn2_b  = (const float*)d_in[10];
  const float* alpha     = (const float*)d_in[11];
  const float* ffn_w1    = (const float*)d_in[12];
  const float* ffn_gn1_g = (const float*)d_in[13];
  const float* ffn_gn1_b = (const float*)d_in[14];
  const float* ffn_w2    = (const float*)d_in[15];
  const float* ffn_gn2_g = (const float*)d_in[16];
  const float* ffn_gn2_b = (const float*)d_in[17];
  float* out = (float*)d_out;

  float* ws = (float*)d_ws;
  float* ll   = ws;              // 1,048,576
  float* high = ws + 1048576;    // 3,145,728
  float* y1   = ws + 4194304;    // 3,145,728 (fused dw+gn out)
  float* qnkv = ws + 7340032;    // 3,145,728 ; qh|kh|vh (fp16) ; reused as pw/h_out
  float* atto = ws + 10485760;   // 1,048,576
  float* proj = ws + 11534336;   // 1,048,576
  float* f1   = ws + 12582912;   // 8,388,608
  float* f3   = ws + 20971520;   // 4,194,304
  uint4* qh = (uint4*)qnkv;
  uint4* kh = (uint4*)(qnkv + 524288);
  uint4* vh = (uint4*)(qnkv + 1048576);
  float* pw = qnkv;

  // 1) DWT (vectorized)
  k_dwt<<<2048, 256, 0, stream>>>(x, ll, high);
  // 2) fused qkv conv + l2norm + fp16 pack
  k_conv_qkv<<<dim3(16, 6, 8), 256, 0, stream>>>(ll, qkv_w, qh, kh, vh);
  // 3) sparse attention (4 q-rows per wave, XCD-swizzled, prefetched)
  k_attn<<<4096, 256, 0, stream>>>((const uint32_t*)qh, kh, vh, atto);
  // 4) proj + groupnorm, s1 = ll + gn(proj)
  k_conv1x1<128, 1, 4><<<dim3(4, 32, 8), 256, 0, stream>>>(atto, proj_w, proj, 128, 1024);
  k_gn<0, true><<<256, 512, 0, stream>>>(proj, ll, proj, attn_gn_g, attn_gn_b,
                                         nullptr, 1.0f, 4, 1024, 10);
  // 5) high enhance: fused dwconv+GN1+silu, pointwise conv, GN2
  k_dwgn<<<256, 1024, 0, stream>>>(high, he_dw_w, he_gn1_g, he_gn1_b, y1);
  k_conv1x1<384, 1, 8><<<dim3(4, 48, 8), 256, 0, stream>>>(y1, he_pw_w, pw, 384, 1024);
  k_gn<0, true><<<256, 512, 0, stream>>>(pw, high, pw, he_gn2_g, he_gn2_b,
                                         alpha, 0.f, 12, 1024, 10);
  // 6) IWT + residual -> out (vectorized)
  k_iwt<<<2048, 256, 0, stream>>>(x, proj, pw, out);
  // 7) FFN (ffn1 OPT=16: input re-reads 2.1 GB -> 1.07 GB)
  k_conv1x1<128, 2, 16><<<dim3(8, 16, 8), 256, 0, stream>>>(out, ffn_w1, f1, 256, 4096);
  k_gn<2, false><<<256, 512, 0, stream>>>(f1, nullptr, f1, ffn_gn1_g, ffn_gn1_b,
                                          nullptr, 0.f, 8, 4096, 12);
  k_conv1x1<256, 2, 8><<<dim3(8, 16, 8), 256, 0, stream>>>(f1, ffn_w2, f3, 128, 4096);
  k_gn<0, true><<<256, 512, 0, stream>>>(f3, out, out, ffn_gn2_g, ffn_gn2_b,
                                         nullptr, 0.1f, 4, 4096, 12);
  (void)in_sizes; (void)n_in; (void)out_size; (void)ws_size;
}